// Round 7
// baseline (105.350 us; speedup 1.0000x reference)
//
#include <hip/hip_runtime.h>
#include <hip/hip_fp16.h>

#define N_NODES 100000
#define N_EDGES 1600000
#define HIDDEN 64
#define RPB 512                                  // rows per coarse bucket
#define NCB ((N_NODES + RPB - 1) / RPB)          // 196 coarse buckets
#define CAP 8960                                 // padded bucket capacity (mean 8163 + 8.8 sigma)
#define NPART 256                                // tier-2 coarse_hist blocks
#define R1_BATCH 4096
#define R1_PER_T (R1_BATCH / 256)                // 16 edges per thread

// ================= PRIMARY PATH =================

// ---------------- P0: convert x to fp16 (streaming, RNE) ---------------------------
__global__ void __launch_bounds__(256) conv_fp16_kernel(const float4* __restrict__ x4,
                                                        ushort4* __restrict__ xh,
                                                        int n4) {
    int i = blockIdx.x * blockDim.x + threadIdx.x;
    const int stride = gridDim.x * blockDim.x;
    for (; i < n4; i += stride) {
        const float4 v = x4[i];
        ushort4 q;
        q.x = __half_as_ushort(__float2half(v.x));
        q.y = __half_as_ushort(__float2half(v.y));
        q.z = __half_as_ushort(__float2half(v.z));
        q.w = __half_as_ushort(__float2half(v.w));
        xh[i] = q;
    }
}

// ---------------- P1: coarse scatter into padded buckets (block-aggregated) --------
// pack: m.x = (row&511)<<17 | col   (col < 2^17), m.y = val bits
__global__ void __launch_bounds__(256) coarse_scatter_pad_kernel(
        const int* __restrict__ rows, const int* __restrict__ cols,
        const float* __restrict__ vals, int* __restrict__ ccursor,
        int2* __restrict__ cbuf) {
    __shared__ int hist[NCB];
    __shared__ int base[NCB];
    __shared__ int lcur[NCB];
    const int t = threadIdx.x;
    const int b0 = blockIdx.x * R1_BATCH;
    for (int i = t; i < NCB; i += 256) { hist[i] = 0; lcur[i] = 0; }
    __syncthreads();

    int  mb[R1_PER_T];
    int2 md[R1_PER_T];
    #pragma unroll
    for (int k = 0; k < R1_PER_T; ++k) {
        const int e = b0 + k * 256 + t;  // coalesced
        if (e < N_EDGES) {
            const int r = rows[e];
            mb[k] = r >> 9;
            md[k] = make_int2(((r & 511) << 17) | cols[e], __float_as_int(vals[e]));
            atomicAdd(&hist[mb[k]], 1);
        } else {
            mb[k] = -1;
        }
    }
    __syncthreads();
    for (int i = t; i < NCB; i += 256) {
        const int c = hist[i];
        base[i] = c ? (i * CAP + atomicAdd(&ccursor[i], c)) : 0;
    }
    __syncthreads();
    #pragma unroll
    for (int k = 0; k < R1_PER_T; ++k) {
        if (mb[k] >= 0) {
            const int rank = atomicAdd(&lcur[mb[k]], 1);
            cbuf[base[mb[k]] + rank] = md[k];
        }
    }
}

// ---------------- P2: exclusive scan of 196 bucket counts --------------------------
__global__ void __launch_bounds__(256) count_scan_kernel(const int* __restrict__ ccursor,
                                                         int* __restrict__ cbase,
                                                         int* __restrict__ offs) {
    __shared__ int s[2][256];
    const int t = threadIdx.x;
    s[0][t] = (t < NCB) ? ccursor[t] : 0;
    __syncthreads();
    int src = 0;
    for (int off = 1; off < 256; off <<= 1) {
        s[1 - src][t] = s[src][t] + (t >= off ? s[src][t - off] : 0);
        __syncthreads();
        src ^= 1;
    }
    if (t <= NCB) cbase[t] = t ? s[src][t - 1] : 0;
    if (t == 0) offs[N_NODES] = N_EDGES;
}

// ---------------- P3: per-bucket LDS row-hist + scan + scatter; writes CSR offs ----
__global__ void __launch_bounds__(1024) fine_bucket_pad_kernel(
        const int2* __restrict__ cbuf, const int* __restrict__ cbase,
        int* __restrict__ offs, int2* __restrict__ ebuf) {
    __shared__ int s[2][RPB];
    __shared__ int lcur[RPB];
    const int b = blockIdx.x;
    const int t = threadIdx.x;
    const int rowbase = b << 9;
    const int src0 = b * CAP;
    const int dst0 = cbase[b];
    const int cnt  = cbase[b + 1] - dst0;

    if (t < RPB) s[0][t] = 0;
    __syncthreads();
    for (int i = t; i < cnt; i += 1024)
        atomicAdd(&s[0][cbuf[src0 + i].x >> 17], 1);
    __syncthreads();
    int src = 0;
    for (int off = 1; off < RPB; off <<= 1) {
        if (t < RPB) s[1 - src][t] = s[src][t] + (t >= off ? s[src][t - off] : 0);
        __syncthreads();
        src ^= 1;
    }
    if (t < RPB) {
        const int excl = dst0 + (t ? s[src][t - 1] : 0);
        const int row = rowbase + t;
        if (row < N_NODES) offs[row] = excl;
        lcur[t] = excl;
    }
    __syncthreads();
    for (int i = t; i < cnt; i += 1024) {
        const int2 m = cbuf[src0 + i];
        const int pos = atomicAdd(&lcur[m.x >> 17], 1);
        ebuf[pos] = make_int2(m.x & 0x1FFFF, m.y);
    }
}

// ---------------- P4: CSR SpMM, fp16 x gather, 4 edges/load, fused ReLU ------------
// lane = g*16 + h: g = edge subgroup (0..3), h covers hidden[4h..4h+3] (ushort4 = 4 halves)
__global__ void __launch_bounds__(256) spmm_csr_relu_h4_kernel(
        const ushort4* __restrict__ xh, const int2* __restrict__ ebuf,
        const int* __restrict__ offs, float4* __restrict__ out4) {
    const int lane = threadIdx.x & 63;
    const int g = lane >> 4;
    const int h = lane & 15;
    const int wave = threadIdx.x >> 6;
    const int r = blockIdx.x * 4 + wave;
    if (r >= N_NODES) return;
    const int start = offs[r];
    const int n = offs[r + 1] - start;

    float4 acc = make_float4(0.f, 0.f, 0.f, 0.f);
    for (int base = 0; base < n; base += 64) {
        const int take = min(64, n - base);
        int2 m = make_int2(0, 0);
        if (base + lane < n) m = ebuf[start + base + lane];  // coalesced meta load
        for (int j = 0; j < take; j += 8) {
            const int j0 = j + g;
            const int j1 = j + 4 + g;
            const bool p0 = j0 < take;
            const bool p1 = j1 < take;
            const int   c0r = __shfl(m.x, j0);
            const float v0r = __int_as_float(__shfl(m.y, j0));
            const int   c1r = __shfl(m.x, j1);
            const float v1r = __int_as_float(__shfl(m.y, j1));
            const int   c0 = p0 ? c0r : 0;
            const float v0 = p0 ? v0r : 0.0f;
            const int   c1 = p1 ? c1r : 0;
            const float v1 = p1 ? v1r : 0.0f;
            const ushort4 qa = xh[(size_t)c0 * 16 + h];   // two 8B loads in flight
            const ushort4 qb = xh[(size_t)c1 * 16 + h];
            acc.x = fmaf(v0, __half2float(__ushort_as_half(qa.x)), acc.x);
            acc.y = fmaf(v0, __half2float(__ushort_as_half(qa.y)), acc.y);
            acc.z = fmaf(v0, __half2float(__ushort_as_half(qa.z)), acc.z);
            acc.w = fmaf(v0, __half2float(__ushort_as_half(qa.w)), acc.w);
            acc.x = fmaf(v1, __half2float(__ushort_as_half(qb.x)), acc.x);
            acc.y = fmaf(v1, __half2float(__ushort_as_half(qb.y)), acc.y);
            acc.z = fmaf(v1, __half2float(__ushort_as_half(qb.z)), acc.z);
            acc.w = fmaf(v1, __half2float(__ushort_as_half(qb.w)), acc.w);
        }
    }
    // fold the 4 edge-subgroups (lanes differing in bits 4,5)
    acc.x += __shfl_xor(acc.x, 16); acc.y += __shfl_xor(acc.y, 16);
    acc.z += __shfl_xor(acc.z, 16); acc.w += __shfl_xor(acc.w, 16);
    acc.x += __shfl_xor(acc.x, 32); acc.y += __shfl_xor(acc.y, 32);
    acc.z += __shfl_xor(acc.z, 32); acc.w += __shfl_xor(acc.w, 32);
    if (lane < 16) {
        float4 o;
        o.x = fmaxf(acc.x, 0.f); o.y = fmaxf(acc.y, 0.f);
        o.z = fmaxf(acc.z, 0.f); o.w = fmaxf(acc.w, 0.f);
        out4[(size_t)r * 16 + h] = o;
    }
}

// ---------------- Tier-1b: fp32-gather spmm (round-6 kernel) -----------------------
__global__ void __launch_bounds__(256) spmm_csr_relu_f4_kernel(
        const float4* __restrict__ x4, const int2* __restrict__ ebuf,
        const int* __restrict__ offs, float4* __restrict__ out4) {
    const int lane = threadIdx.x & 63;
    const int g = lane >> 4;
    const int h = lane & 15;
    const int wave = threadIdx.x >> 6;
    const int r = blockIdx.x * 4 + wave;
    if (r >= N_NODES) return;
    const int start = offs[r];
    const int n = offs[r + 1] - start;

    float4 acc = make_float4(0.f, 0.f, 0.f, 0.f);
    for (int base = 0; base < n; base += 64) {
        const int take = min(64, n - base);
        int2 m = make_int2(0, 0);
        if (base + lane < n) m = ebuf[start + base + lane];
        for (int j = 0; j < take; j += 8) {
            const int j0 = j + g;
            const int j1 = j + 4 + g;
            const bool p0 = j0 < take;
            const bool p1 = j1 < take;
            const int   c0 = p0 ? __shfl(m.x, j0) : 0;
            const float v0 = p0 ? __int_as_float(__shfl(m.y, j0)) : 0.0f;
            const int   c1 = p1 ? __shfl(m.x, j1) : 0;
            const float v1 = p1 ? __int_as_float(__shfl(m.y, j1)) : 0.0f;
            const float4 a = x4[(size_t)c0 * 16 + h];
            const float4 bq = x4[(size_t)c1 * 16 + h];
            acc.x = fmaf(v0, a.x, acc.x);  acc.y = fmaf(v0, a.y, acc.y);
            acc.z = fmaf(v0, a.z, acc.z);  acc.w = fmaf(v0, a.w, acc.w);
            acc.x = fmaf(v1, bq.x, acc.x); acc.y = fmaf(v1, bq.y, acc.y);
            acc.z = fmaf(v1, bq.z, acc.z); acc.w = fmaf(v1, bq.w, acc.w);
        }
    }
    acc.x += __shfl_xor(acc.x, 16); acc.y += __shfl_xor(acc.y, 16);
    acc.z += __shfl_xor(acc.z, 16); acc.w += __shfl_xor(acc.w, 16);
    acc.x += __shfl_xor(acc.x, 32); acc.y += __shfl_xor(acc.y, 32);
    acc.z += __shfl_xor(acc.z, 32); acc.w += __shfl_xor(acc.w, 32);
    if (lane < 16) {
        float4 o;
        o.x = fmaxf(acc.x, 0.f); o.y = fmaxf(acc.y, 0.f);
        o.z = fmaxf(acc.z, 0.f); o.w = fmaxf(acc.w, 0.f);
        out4[(size_t)r * 16 + h] = o;
    }
}

// ================= TIER-3 fallback =================
__global__ void spmm_scatter_kernel(const float* __restrict__ x,
                                    const int* __restrict__ rows,
                                    const int* __restrict__ cols,
                                    const float* __restrict__ vals,
                                    float* __restrict__ f) {
    const int lane = threadIdx.x & 63;
    const int wave = (blockIdx.x * blockDim.x + threadIdx.x) >> 6;
    const int nWaves = (gridDim.x * blockDim.x) >> 6;
    for (int e = wave; e < N_EDGES; e += nWaves)
        atomicAdd(&f[rows[e] * HIDDEN + lane], vals[e] * x[cols[e] * HIDDEN + lane]);
}
__global__ void relu_inplace_kernel(float4* __restrict__ f, int n4) {
    int i = blockIdx.x * blockDim.x + threadIdx.x;
    const int stride = gridDim.x * blockDim.x;
    for (; i < n4; i += stride) {
        float4 v = f[i];
        v.x = fmaxf(v.x, 0.0f); v.y = fmaxf(v.y, 0.0f);
        v.z = fmaxf(v.z, 0.0f); v.w = fmaxf(v.w, 0.0f);
        f[i] = v;
    }
}

extern "C" void kernel_launch(void* const* d_in, const int* in_sizes, int n_in,
                              void* d_out, int out_size, void* d_ws, size_t ws_size,
                              hipStream_t stream) {
    const float* x    = (const float*)d_in[1];
    const int*   rows = (const int*)d_in[2];
    const int*   cols = (const int*)d_in[3];
    const float* vals = (const float*)d_in[4];
    float* out = (float*)d_out;
    char* ws = (char*)d_ws;

    // Shared prefix layout: ccursor[NCB] | cbase[NCB+1] | offs[N+1] | cbuf[NCB*CAP] | ebuf[E] | xh[N*64]
    const size_t ccursor_off = 0;
    const size_t cbase_off   = ccursor_off + (size_t)NCB * 4;
    const size_t offs_off    = cbase_off + (size_t)(NCB + 1) * 4;
    size_t cbuf_off = offs_off + (size_t)(N_NODES + 1) * 4;
    cbuf_off = (cbuf_off + 15) & ~(size_t)15;
    const size_t ebuf_off = cbuf_off + (size_t)NCB * CAP * 8;
    const size_t xh_off   = ebuf_off + (size_t)N_EDGES * 8;     // 16B-aligned (E*8 is)
    const size_t ws_t1  = xh_off + (size_t)N_NODES * HIDDEN * 2;  // + fp16 x
    const size_t ws_t1b = ebuf_off + (size_t)N_EDGES * 8;         // round-6 need

    if (ws_size >= ws_t1b) {
        int*  ccursor = (int*)(ws + ccursor_off);
        int*  cbase   = (int*)(ws + cbase_off);
        int*  offs    = (int*)(ws + offs_off);
        int2* cbuf    = (int2*)(ws + cbuf_off);
        int2* ebuf    = (int2*)(ws + ebuf_off);
        const bool fp16_path = (ws_size >= ws_t1);

        hipMemsetAsync(ccursor, 0, (size_t)NCB * 4, stream);
        if (fp16_path) {
            ushort4* xh = (ushort4*)(ws + xh_off);
            conv_fp16_kernel<<<2048, 256, 0, stream>>>((const float4*)x, xh,
                                                       N_NODES * HIDDEN / 4);
        }
        coarse_scatter_pad_kernel<<<(N_EDGES + R1_BATCH - 1) / R1_BATCH, 256, 0, stream>>>(
            rows, cols, vals, ccursor, cbuf);
        count_scan_kernel<<<1, 256, 0, stream>>>(ccursor, cbase, offs);
        fine_bucket_pad_kernel<<<NCB, 1024, 0, stream>>>(cbuf, cbase, offs, ebuf);
        if (fp16_path) {
            const ushort4* xh = (const ushort4*)(ws + xh_off);
            spmm_csr_relu_h4_kernel<<<N_NODES / 4, 256, 0, stream>>>(
                xh, ebuf, offs, (float4*)out);
        } else {
            spmm_csr_relu_f4_kernel<<<N_NODES / 4, 256, 0, stream>>>(
                (const float4*)x, ebuf, offs, (float4*)out);
        }
        return;
    }

    // Tier-3: global-atomic scatter
    hipMemsetAsync(d_out, 0, (size_t)N_NODES * HIDDEN * sizeof(float), stream);
    spmm_scatter_kernel<<<2048, 256, 0, stream>>>(x, rows, cols, vals, out);
    relu_inplace_kernel<<<2048, 256, 0, stream>>>((float4*)d_out,
                                                  (N_NODES * HIDDEN) / 4);
}